// Round 1
// baseline (193.699 us; speedup 1.0000x reference)
//
#include <hip/hip_runtime.h>
#include <cstdint>
#include <cstddef>

typedef unsigned short u16;
typedef __attribute__((ext_vector_type(8))) short short8;
typedef __attribute__((ext_vector_type(8))) u16 ushort8;
typedef __attribute__((ext_vector_type(4))) float float4_t;

#define BB 8
#define NN 8192
#define DD 64
#define NTILES 64          // 8192 / 128
#define TILE_SHORTS 8192   // 128 rows * 64 k

__device__ inline u16 f32_to_bf16(float f) {
  unsigned u = __float_as_uint(f);
  u += 0x7FFFu + ((u >> 16) & 1u);   // RNE
  return (u16)(u >> 16);
}

__device__ inline unsigned enc_ord(float f) {
  unsigned u = __float_as_uint(f);
  return (u & 0x80000000u) ? ~u : (u | 0x80000000u);
}
__device__ inline float dec_ord(unsigned u) {
  return __uint_as_float((u & 0x80000000u) ? (u & 0x7fffffffu) : ~u);
}

// ---------------------------------------------------------------------------
// K0: zero colmax (atomic fallback path only)
// ---------------------------------------------------------------------------
__global__ void zero_kernel(unsigned* __restrict__ p, int n) {
  int i = blockIdx.x * 256 + threadIdx.x;
  if (i < n) p[i] = 0u;
}

// ---------------------------------------------------------------------------
// K1: fp32 -> bf16, pre-swizzled into MFMA fragment chunk order + 0.5*|v|^2
// Chunk layout per 128x64 tile: [I(8)][s(2)] chunks of 1KB; within a chunk
// lane l (l=q*16+rl) holds row I*16+rl, k = s*32+q*8+j  (j=0..7, 16B).
// ---------------------------------------------------------------------------
__global__ __launch_bounds__(256) void pre_kernel(
    const float* __restrict__ x, const float* __restrict__ y,
    u16* __restrict__ xs, u16* __restrict__ ys,
    float* __restrict__ x2h, float* __restrict__ y2h)
{
  const int bid = blockIdx.x;          // 512 blocks: 0..255 -> x, 256..511 -> y
  const int tid = threadIdx.x;
  const bool isY = bid >= 256;
  const float* src = isY ? y : x;
  u16* dst = isY ? ys : xs;
  float* s2 = isY ? y2h : x2h;

  const int row = ((bid & 255) << 8) | tid;      // 0..65535 (= b*8192 + n)
  const float4* rp = (const float4*)(src + (size_t)row * DD);
  float buf[DD];
  float ss = 0.f;
#pragma unroll
  for (int k = 0; k < 16; ++k) {
    float4 f = rp[k];
    buf[4*k+0] = f.x; buf[4*k+1] = f.y; buf[4*k+2] = f.z; buf[4*k+3] = f.w;
    ss += f.x*f.x + f.y*f.y + f.z*f.z + f.w*f.w;
  }
  s2[row] = 0.5f * ss;

  const int b  = row >> 13;
  const int n  = row & (NN - 1);
  const int nt = n >> 7;
  const int I  = (n >> 4) & 7;
  const int rl = n & 15;
  u16* tb = dst + (size_t)((b << 6) | nt) * TILE_SHORTS;
#pragma unroll
  for (int s = 0; s < 2; ++s)
#pragma unroll
    for (int qq = 0; qq < 4; ++qq) {
      ushort8 o;
#pragma unroll
      for (int j = 0; j < 8; ++j) o[j] = f32_to_bf16(buf[s*32 + qq*8 + j]);
      *(ushort8*)(tb + (I*2 + s)*512 + (qq*16 + rl)*8) = o;
    }
}

// ---------------------------------------------------------------------------
// K2: main. Block = 256 thr (4 waves, 2x2 of 64x64 wave tiles), tile 128 rows,
// sweeps all 64 col-tiles. A-frags pinned in registers; y double-buffered LDS
// via global_load_lds. Row-max in regs (exact); per-tile col-max partials.
// ---------------------------------------------------------------------------
__global__ __launch_bounds__(256, 2) void main_kernel(
    const u16* __restrict__ xs, const u16* __restrict__ ys,
    const float* __restrict__ x2h, const float* __restrict__ y2h,
    float* __restrict__ a_min, float* __restrict__ colpart,
    unsigned* __restrict__ colmax_u, const int use_part)
{
  __shared__ __align__(16) u16 ytile[2][TILE_SHORTS];   // 2 x 16KB
  __shared__ float colbuf[2][2][128];                   // [parity][wr][col]
  __shared__ float rowbuf[2][128];                      // [wc][row]

  const int bid = blockIdx.x;            // 512
  const int b   = bid & 7;               // XCD-affine: blockIdx%8 ~ XCD id
  const int nt  = bid >> 3;
  const int tid = threadIdx.x;
  const int w = tid >> 6, lane = tid & 63;
  const int wr = w >> 1, wc = w & 1;
  const int l15 = lane & 15, q = lane >> 4;
  const int n0 = nt << 7;

  // ---- A fragments: load once, keep in registers all 64 iterations ----
  const u16* xs_tile = xs + (size_t)((b << 6) | nt) * TILE_SHORTS;
  short8 afr[4][2];
#pragma unroll
  for (int i = 0; i < 4; ++i)
#pragma unroll
    for (int s = 0; s < 2; ++s)
      afr[i][s] = *(const short8*)(xs_tile + ((wr*4 + i)*2 + s)*512 + lane*8);

  float x2r[4][4];
  const float* x2b = x2h + b*NN + n0 + wr*64;
#pragma unroll
  for (int i = 0; i < 4; ++i)
#pragma unroll
    for (int r = 0; r < 4; ++r) x2r[i][r] = x2b[i*16 + q*4 + r];

  float rowmax[4][4];
#pragma unroll
  for (int i = 0; i < 4; ++i)
#pragma unroll
    for (int r = 0; r < 4; ++r) rowmax[i][r] = -3.0e38f;

  const float* y2b = y2h + b*NN;
  const u16* ys_b  = ys + (size_t)(b << 6) * TILE_SHORTS;

  // ---- stage tile 0 ----
#pragma unroll
  for (int c = 0; c < 4; ++c) {
    const int chunk = w*4 + c;
    __builtin_amdgcn_global_load_lds(
        (const __attribute__((address_space(1))) void*)(ys_b + chunk*512 + lane*8),
        (__attribute__((address_space(3))) void*)(&ytile[0][chunk*512]),
        16, 0, 0);
  }
  __syncthreads();

  const float4_t zero4 = {0.f, 0.f, 0.f, 0.f};
  int cur = 0;
  for (int mt = 0; mt < NTILES; ++mt) {
    // prefetch next y tile into the other buffer (completes at the barrier)
    if (mt + 1 < NTILES) {
      const u16* g = ys_b + (size_t)(mt + 1) * TILE_SHORTS;
#pragma unroll
      for (int c = 0; c < 4; ++c) {
        const int chunk = w*4 + c;
        __builtin_amdgcn_global_load_lds(
            (const __attribute__((address_space(1))) void*)(g + chunk*512 + lane*8),
            (__attribute__((address_space(3))) void*)(&ytile[cur ^ 1][chunk*512]),
            16, 0, 0);
      }
    }

    float y2c[4];
#pragma unroll
    for (int j = 0; j < 4; ++j) y2c[j] = y2b[(mt << 7) + wc*64 + j*16 + l15];

    short8 bf[4][2];
#pragma unroll
    for (int j = 0; j < 4; ++j)
#pragma unroll
      for (int s = 0; s < 2; ++s)
        bf[j][s] = *(const short8*)(&ytile[cur][((wc*4 + j)*2 + s)*512 + lane*8]);

    float4_t acc[4][4];
#pragma unroll
    for (int i = 0; i < 4; ++i)
#pragma unroll
      for (int j = 0; j < 4; ++j)
        acc[i][j] = __builtin_amdgcn_mfma_f32_16x16x32_bf16(afr[i][0], bf[j][0], zero4, 0, 0, 0);
#pragma unroll
    for (int i = 0; i < 4; ++i)
#pragma unroll
      for (int j = 0; j < 4; ++j)
        acc[i][j] = __builtin_amdgcn_mfma_f32_16x16x32_bf16(afr[i][1], bf[j][1], acc[i][j], 0, 0, 0);

    // epilogue: rowmax = max(xy - y2/2), colmax = max(xy - x2/2)
    float cmax[4] = {-3.0e38f, -3.0e38f, -3.0e38f, -3.0e38f};
#pragma unroll
    for (int i = 0; i < 4; ++i)
#pragma unroll
      for (int j = 0; j < 4; ++j)
#pragma unroll
        for (int r = 0; r < 4; ++r) {
          float v = acc[i][j][r];
          rowmax[i][r] = fmaxf(rowmax[i][r], v - y2c[j]);
          cmax[j]      = fmaxf(cmax[j],      v - x2r[i][r]);
        }
#pragma unroll
    for (int j = 0; j < 4; ++j) {
      cmax[j] = fmaxf(cmax[j], __shfl_xor(cmax[j], 16));
      cmax[j] = fmaxf(cmax[j], __shfl_xor(cmax[j], 32));
    }
    // lane l holds final col-max for local col l in cmax[l>>4]
    float lo = (q & 1) ? cmax[1] : cmax[0];
    float hi = (q & 1) ? cmax[3] : cmax[2];
    float cv = (q & 2) ? hi : lo;
    colbuf[mt & 1][wr][wc*64 + lane] = cv;
    __syncthreads();
    if (tid < 128) {
      float v = fmaxf(colbuf[mt & 1][0][tid], colbuf[mt & 1][1][tid]);
      const int m = (mt << 7) + tid;
      if (use_part) colpart[(size_t)((b << 6) | nt) * NN + m] = v;
      else          atomicMax(&colmax_u[b*NN + m], enc_ord(v));
    }
    cur ^= 1;
  }

  // ---- row side finalize: a[n] = sqrt(2*(x2h - rowmax)) ----
#pragma unroll
  for (int i = 0; i < 4; ++i)
#pragma unroll
    for (int r = 0; r < 4; ++r) {
      float v = rowmax[i][r];
      v = fmaxf(v, __shfl_xor(v, 1));
      v = fmaxf(v, __shfl_xor(v, 2));
      v = fmaxf(v, __shfl_xor(v, 4));
      v = fmaxf(v, __shfl_xor(v, 8));
      rowmax[i][r] = v;
    }
  if (l15 == 0) {
#pragma unroll
    for (int i = 0; i < 4; ++i)
#pragma unroll
      for (int r = 0; r < 4; ++r)
        rowbuf[wc][wr*64 + i*16 + q*4 + r] = rowmax[i][r];
  }
  __syncthreads();
  if (tid < 128) {
    float v  = fmaxf(rowbuf[0][tid], rowbuf[1][tid]);
    float x2 = x2h[b*NN + n0 + tid];
    a_min[b*NN + n0 + tid] = sqrtf(fmaxf(2.f*(x2 - v), 0.f));
  }
}

// ---------------------------------------------------------------------------
// K3: col-side reduce over nt partials + sqrt, plus a_min slice; block sums.
// ---------------------------------------------------------------------------
__global__ __launch_bounds__(256) void reduce_kernel(
    const float* __restrict__ colpart, const unsigned* __restrict__ colmax_u,
    const float* __restrict__ y2h, const float* __restrict__ a_min,
    float* __restrict__ partials, const int use_part)
{
  const int bid = blockIdx.x;          // 256
  const int tid = threadIdx.x;
  const int b = bid >> 5, mc = bid & 31;
  const int m = (mc << 8) + tid;

  float v;
  if (use_part) {
    v = -3.0e38f;
#pragma unroll 4
    for (int nt = 0; nt < 64; ++nt)
      v = fmaxf(v, colpart[(size_t)((b << 6) | nt) * NN + m]);
  } else {
    v = dec_ord(colmax_u[b*NN + m]);
  }
  float s = sqrtf(fmaxf(2.f*(y2h[b*NN + m] - v), 0.f));
  s += a_min[bid*256 + tid];

#pragma unroll
  for (int d = 1; d < 64; d <<= 1) s += __shfl_xor(s, d);
  __shared__ float wsum[4];
  if ((tid & 63) == 0) wsum[tid >> 6] = s;
  __syncthreads();
  if (tid == 0) partials[bid] = wsum[0] + wsum[1] + wsum[2] + wsum[3];
}

// ---------------------------------------------------------------------------
// K4: final scalar
// ---------------------------------------------------------------------------
__global__ void final_kernel(const float* __restrict__ partials, float* __restrict__ out) {
  const int tid = threadIdx.x;         // 256
  float s = partials[tid];
#pragma unroll
  for (int d = 1; d < 64; d <<= 1) s += __shfl_xor(s, d);
  __shared__ float wsum[4];
  if ((tid & 63) == 0) wsum[tid >> 6] = s;
  __syncthreads();
  if (tid == 0) out[0] = (wsum[0] + wsum[1] + wsum[2] + wsum[3]) * (1.0f / 65536.0f);
}

// ---------------------------------------------------------------------------
extern "C" void kernel_launch(void* const* d_in, const int* in_sizes, int n_in,
                              void* d_out, int out_size, void* d_ws, size_t ws_size,
                              hipStream_t stream) {
  const float* x = (const float*)d_in[0];
  const float* y = (const float*)d_in[1];
  float* out = (float*)d_out;

  char* p = (char*)d_ws;
  u16* xs = (u16*)p;            p += (size_t)512 * 16384;   // 8 MiB
  u16* ys = (u16*)p;            p += (size_t)512 * 16384;   // 8 MiB
  float* x2h = (float*)p;       p += (size_t)65536 * 4;
  float* y2h = (float*)p;       p += (size_t)65536 * 4;
  float* a_min = (float*)p;     p += (size_t)65536 * 4;
  float* partials = (float*)p;  p += 4096;
  unsigned* colmax_u = (unsigned*)p;   // atomic path: 256 KiB
  float* colpart = (float*)p;          // partial path: 16 MiB
  const size_t base = (size_t)(p - (char*)d_ws);
  const int use_part = (ws_size >= base + (size_t)16777216) ? 1 : 0;

  if (!use_part)
    zero_kernel<<<dim3(256), dim3(256), 0, stream>>>(colmax_u, 65536);

  pre_kernel<<<dim3(512), dim3(256), 0, stream>>>(x, y, xs, ys, x2h, y2h);
  main_kernel<<<dim3(512), dim3(256), 0, stream>>>(xs, ys, x2h, y2h, a_min,
                                                   colpart, colmax_u, use_part);
  reduce_kernel<<<dim3(256), dim3(256), 0, stream>>>(colpart, colmax_u, y2h,
                                                     a_min, partials, use_part);
  final_kernel<<<dim3(1), dim3(256), 0, stream>>>(partials, out);
}

// Round 2
// 178.355 us; speedup vs baseline: 1.0860x; 1.0860x over previous
//
#include <hip/hip_runtime.h>
#include <cstdint>
#include <cstddef>

typedef unsigned short u16;
typedef __attribute__((ext_vector_type(8))) short short8;
typedef __attribute__((ext_vector_type(8))) u16 ushort8;
typedef __attribute__((ext_vector_type(4))) float float4_t;

#define BB 8
#define NN 8192
#define DD 64
#define NTILES 64            // 8192 / 128 column tiles
#define TILE_SHORTS 8192     // 128 rows * 64 k  (bf16)
#define TILE_EXT 8448        // + 256 shorts (512B) of fp32 y2 ext

__device__ inline u16 f32_to_bf16(float f) {
  unsigned u = __float_as_uint(f);
  u += 0x7FFFu + ((u >> 16) & 1u);   // RNE
  return (u16)(u >> 16);
}

__device__ inline unsigned enc_ord(float f) {
  unsigned u = __float_as_uint(f);
  return (u & 0x80000000u) ? ~u : (u | 0x80000000u);
}
__device__ inline float dec_ord(unsigned u) {
  return __uint_as_float((u & 0x80000000u) ? (u & 0x7fffffffu) : ~u);
}

// ---------------------------------------------------------------------------
// K0: zero max buffers (atomic fallback path only)
// ---------------------------------------------------------------------------
__global__ void zero_kernel(unsigned* __restrict__ p, int n) {
  int i = blockIdx.x * 256 + threadIdx.x;
  if (i < n) p[i] = 0u;
}

// ---------------------------------------------------------------------------
// K1: fp32 -> bf16 pre-swizzle into MFMA fragment chunk order + 0.5*|v|^2.
// 64 rows/block, 4 threads/row -> fully coalesced 4KB/wave global loads.
// Chunk layout per 128x64 tile: [I(8)][s(2)] chunks of 1KB; within a chunk
// lane l (l=q*16+rl) holds row I*16+rl, k = s*32+q*8+j (j=0..7, 16B).
// ---------------------------------------------------------------------------
__global__ __launch_bounds__(256) void pre_kernel(
    const float* __restrict__ x, const float* __restrict__ y,
    u16* __restrict__ xs, u16* __restrict__ ys,
    float* __restrict__ x2h, float* __restrict__ y2h)
{
  const int bid = blockIdx.x;          // 2048: 0..1023 -> x, 1024..2047 -> y
  const int tid = threadIdx.x;
  const bool isY = bid >= 1024;
  const float* src = isY ? y : x;
  u16* dst = isY ? ys : xs;
  float* s2 = isY ? y2h : x2h;

  const int row = ((bid & 1023) << 6) | (tid >> 2);   // 0..65535 = b*8192+n
  const int kq  = tid & 3;                            // 16-float chunk of D

  const float4* rp = (const float4*)(src + (size_t)row * DD + kq * 16);
  float buf[16];
  float ss = 0.f;
#pragma unroll
  for (int k = 0; k < 4; ++k) {
    float4 f = rp[k];
    buf[4*k+0] = f.x; buf[4*k+1] = f.y; buf[4*k+2] = f.z; buf[4*k+3] = f.w;
    ss += f.x*f.x + f.y*f.y + f.z*f.z + f.w*f.w;
  }
  ss += __shfl_xor(ss, 1);
  ss += __shfl_xor(ss, 2);
  if (kq == 0) s2[row] = 0.5f * ss;

  const int b  = row >> 13;
  const int n  = row & (NN - 1);
  const int nt = n >> 7;
  const int I  = (n >> 4) & 7;
  const int rl = n & 15;
  const int s  = kq >> 1;              // which K-half (MFMA index)
  const int qq0 = (kq & 1) * 2;
  u16* tb = dst + (size_t)((b << 6) | nt) * TILE_SHORTS;
#pragma unroll
  for (int t = 0; t < 2; ++t) {
    ushort8 o;
#pragma unroll
    for (int j = 0; j < 8; ++j) o[j] = f32_to_bf16(buf[t*8 + j]);
    *(ushort8*)(tb + (I*2 + s)*512 + ((qq0 + t)*16 + rl)*8) = o;
  }
}

// ---------------------------------------------------------------------------
// K2: main. Block = 256 thr (4 waves, 2x2 of 64x64 wave tiles), 128-row tile,
// sweeps its third of the 64 col-tiles (grid 1536 = 8 b x 64 nt x 3 h).
// acc = xy - x2/2 via fp32 C-init (exact, zero VALU). Col side = pure max.
// y2 staged into LDS with the tile (no per-iter global loads in vmcnt queue).
// ---------------------------------------------------------------------------
__global__ __launch_bounds__(256, 3) void main_kernel(
    const u16* __restrict__ xs, const u16* __restrict__ ys,
    const float* __restrict__ x2h, const float* __restrict__ y2h,
    float* __restrict__ rowpart, float* __restrict__ colpart,
    unsigned* __restrict__ rowmax_u, unsigned* __restrict__ colmax_u,
    const int use_part)
{
  __shared__ __align__(16) u16 ytile[2][TILE_EXT];   // 2 x 16.5KB
  __shared__ float colbuf[2][2][128];
  __shared__ float rowbuf[2][128];

  const int bid = blockIdx.x;            // 1536
  const int b   = bid & 7;               // XCD-affine
  const int nt  = (bid >> 3) & 63;
  const int h   = bid >> 9;              // 0..2
  const int mt_start = (h == 0) ? 0 : (h == 1 ? 22 : 43);
  const int mt_end   = (h == 0) ? 22 : (h == 1 ? 43 : 64);

  const int tid = threadIdx.x;
  const int w = tid >> 6, lane = tid & 63;
  const int wr = w >> 1, wc = w & 1;
  const int l15 = lane & 15, q = lane >> 4;
  const int n0 = nt << 7;

  // ---- A fragments: load once, keep in registers for the whole sweep ----
  const u16* xs_tile = xs + (size_t)((b << 6) | nt) * TILE_SHORTS;
  short8 afr[4][2];
#pragma unroll
  for (int i = 0; i < 4; ++i)
#pragma unroll
    for (int s = 0; s < 2; ++s)
      afr[i][s] = *(const short8*)(xs_tile + ((wr*4 + i)*2 + s)*512 + lane*8);

  // ---- C-init quads: -x2/2 per row (fp32 exact) ----
  float4_t negx2[4];
  const float* x2b = x2h + b*NN + n0 + wr*64;
#pragma unroll
  for (int i = 0; i < 4; ++i) {
    float4_t v = *(const float4_t*)(x2b + i*16 + q*4);
    negx2[i] = {-v[0], -v[1], -v[2], -v[3]};
  }

  float rowmax[4][4];
#pragma unroll
  for (int i = 0; i < 4; ++i)
#pragma unroll
    for (int r = 0; r < 4; ++r) rowmax[i][r] = -3.0e38f;

  const float* y2b = y2h + b*NN;
  const u16* ys_b  = ys + (size_t)(b << 6) * TILE_SHORTS;

  // ---- stage first tile (16 data chunks + 512B y2 ext) ----
  {
    const u16* g = ys_b + (size_t)mt_start * TILE_SHORTS;
#pragma unroll
    for (int c = 0; c < 4; ++c) {
      const int chunk = w*4 + c;
      __builtin_amdgcn_global_load_lds(
          (const __attribute__((address_space(1))) void*)(g + chunk*512 + lane*8),
          (__attribute__((address_space(3))) void*)(&ytile[0][chunk*512]),
          16, 0, 0);
    }
    if (w == 0 && lane < 32)
      __builtin_amdgcn_global_load_lds(
          (const __attribute__((address_space(1))) void*)(y2b + mt_start*128 + lane*4),
          (__attribute__((address_space(3))) void*)(&ytile[0][TILE_SHORTS]),
          16, 0, 0);
  }
  __syncthreads();

  int cur = 0;
  for (int mt = mt_start; mt < mt_end; ++mt) {
    // prefetch next tile into the other buffer (drained by the end barrier)
    if (mt + 1 < mt_end) {
      const u16* g = ys_b + (size_t)(mt + 1) * TILE_SHORTS;
#pragma unroll
      for (int c = 0; c < 4; ++c) {
        const int chunk = w*4 + c;
        __builtin_amdgcn_global_load_lds(
            (const __attribute__((address_space(1))) void*)(g + chunk*512 + lane*8),
            (__attribute__((address_space(3))) void*)(&ytile[cur ^ 1][chunk*512]),
            16, 0, 0);
      }
      if (w == 0 && lane < 32)
        __builtin_amdgcn_global_load_lds(
            (const __attribute__((address_space(1))) void*)(y2b + (mt+1)*128 + lane*4),
            (__attribute__((address_space(3))) void*)(&ytile[cur ^ 1][TILE_SHORTS]),
            16, 0, 0);
    }

    const float* y2t = (const float*)&ytile[cur][TILE_SHORTS];
    float y2c[4];
#pragma unroll
    for (int j = 0; j < 4; ++j) y2c[j] = y2t[wc*64 + j*16 + l15];

    short8 bf[4][2];
#pragma unroll
    for (int j = 0; j < 4; ++j)
#pragma unroll
      for (int s = 0; s < 2; ++s)
        bf[j][s] = *(const short8*)(&ytile[cur][((wc*4 + j)*2 + s)*512 + lane*8]);

    // acc = xy - x2/2  (C-init carries the exact fp32 -x2/2)
    float4_t acc[4][4];
#pragma unroll
    for (int i = 0; i < 4; ++i)
#pragma unroll
      for (int j = 0; j < 4; ++j)
        acc[i][j] = __builtin_amdgcn_mfma_f32_16x16x32_bf16(afr[i][0], bf[j][0], negx2[i], 0, 0, 0);
#pragma unroll
    for (int i = 0; i < 4; ++i)
#pragma unroll
      for (int j = 0; j < 4; ++j)
        acc[i][j] = __builtin_amdgcn_mfma_f32_16x16x32_bf16(afr[i][1], bf[j][1], acc[i][j], 0, 0, 0);

    // col side: pure max of acc
    float cmax[4];
#pragma unroll
    for (int j = 0; j < 4; ++j) {
      float m0 = fmaxf(fmaxf(acc[0][j][0], acc[0][j][1]), fmaxf(acc[0][j][2], acc[0][j][3]));
      float m1 = fmaxf(fmaxf(acc[1][j][0], acc[1][j][1]), fmaxf(acc[1][j][2], acc[1][j][3]));
      float m2 = fmaxf(fmaxf(acc[2][j][0], acc[2][j][1]), fmaxf(acc[2][j][2], acc[2][j][3]));
      float m3 = fmaxf(fmaxf(acc[3][j][0], acc[3][j][1]), fmaxf(acc[3][j][2], acc[3][j][3]));
      cmax[j] = fmaxf(fmaxf(m0, m1), fmaxf(m2, m3));
    }
    // row side: rowmax = max(acc - y2/2) = -min(d^2)/2
#pragma unroll
    for (int i = 0; i < 4; ++i)
#pragma unroll
      for (int r = 0; r < 4; ++r) {
        float t0 = acc[i][0][r] - y2c[0];
        float t1 = acc[i][1][r] - y2c[1];
        float t2 = acc[i][2][r] - y2c[2];
        float t3 = acc[i][3][r] - y2c[3];
        rowmax[i][r] = fmaxf(fmaxf(rowmax[i][r], fmaxf(t0, t1)), fmaxf(t2, t3));
      }

#pragma unroll
    for (int j = 0; j < 4; ++j) {
      cmax[j] = fmaxf(cmax[j], __shfl_xor(cmax[j], 16));
      cmax[j] = fmaxf(cmax[j], __shfl_xor(cmax[j], 32));
    }
    float lo = (q & 1) ? cmax[1] : cmax[0];
    float hi = (q & 1) ? cmax[3] : cmax[2];
    float cv = (q & 2) ? hi : lo;
    colbuf[mt & 1][wr][wc*64 + lane] = cv;
    __syncthreads();
    if (tid < 128) {
      float v = fmaxf(colbuf[mt & 1][0][tid], colbuf[mt & 1][1][tid]);
      const int m = (mt << 7) + tid;
      if (use_part) colpart[(size_t)((b << 6) | nt) * NN + m] = v;
      else          atomicMax(&colmax_u[b*NN + m], enc_ord(v));
    }
    cur ^= 1;
  }

  // ---- row side finalize: cross-lane over l15, combine wc halves ----
#pragma unroll
  for (int i = 0; i < 4; ++i)
#pragma unroll
    for (int r = 0; r < 4; ++r) {
      float v = rowmax[i][r];
      v = fmaxf(v, __shfl_xor(v, 1));
      v = fmaxf(v, __shfl_xor(v, 2));
      v = fmaxf(v, __shfl_xor(v, 4));
      v = fmaxf(v, __shfl_xor(v, 8));
      rowmax[i][r] = v;
    }
  if (l15 == 0) {
#pragma unroll
    for (int i = 0; i < 4; ++i)
#pragma unroll
      for (int r = 0; r < 4; ++r)
        rowbuf[wc][wr*64 + i*16 + q*4 + r] = rowmax[i][r];
  }
  __syncthreads();
  if (tid < 128) {
    float v = fmaxf(rowbuf[0][tid], rowbuf[1][tid]);   // = -min(d^2)/2 partial
    if (use_part) rowpart[(size_t)(h*512 + (b << 6) + nt) * 128 + tid] = v;
    else          atomicMax(&rowmax_u[b*NN + n0 + tid], enc_ord(v));
  }
}

// ---------------------------------------------------------------------------
// K3: combine partials: col over 64 nt + sqrt; row over 3 h + sqrt; block sums
// ---------------------------------------------------------------------------
__global__ __launch_bounds__(256) void reduce_kernel(
    const float* __restrict__ rowpart, const float* __restrict__ colpart,
    const unsigned* __restrict__ rowmax_u, const unsigned* __restrict__ colmax_u,
    const float* __restrict__ y2h,
    float* __restrict__ partials, const int use_part)
{
  const int bid = blockIdx.x;          // 256
  const int tid = threadIdx.x;
  const int g = bid*256 + tid;         // 0..65535
  const int b = g >> 13, m = g & (NN - 1);

  float vc, vr;
  if (use_part) {
    vc = -3.0e38f;
#pragma unroll 8
    for (int nt = 0; nt < 64; ++nt)
      vc = fmaxf(vc, colpart[(size_t)((b << 6) | nt) * NN + m]);
    const int nt = m >> 7, r = m & 127;
    float r0 = rowpart[(size_t)(0*512 + (b << 6) + nt) * 128 + r];
    float r1 = rowpart[(size_t)(1*512 + (b << 6) + nt) * 128 + r];
    float r2 = rowpart[(size_t)(2*512 + (b << 6) + nt) * 128 + r];
    vr = fmaxf(fmaxf(r0, r1), r2);
  } else {
    vc = dec_ord(colmax_u[g]);
    vr = dec_ord(rowmax_u[g]);
  }
  float s = sqrtf(fmaxf(2.f*(y2h[g] - vc), 0.f))   // nearest-x for this y
          + sqrtf(fmaxf(-2.f*vr, 0.f));            // nearest-y for this x

#pragma unroll
  for (int d = 1; d < 64; d <<= 1) s += __shfl_xor(s, d);
  __shared__ float wsum[4];
  if ((tid & 63) == 0) wsum[tid >> 6] = s;
  __syncthreads();
  if (tid == 0) partials[bid] = wsum[0] + wsum[1] + wsum[2] + wsum[3];
}

// ---------------------------------------------------------------------------
// K4: final scalar
// ---------------------------------------------------------------------------
__global__ void final_kernel(const float* __restrict__ partials, float* __restrict__ out) {
  const int tid = threadIdx.x;         // 256
  float s = partials[tid];
#pragma unroll
  for (int d = 1; d < 64; d <<= 1) s += __shfl_xor(s, d);
  __shared__ float wsum[4];
  if ((tid & 63) == 0) wsum[tid >> 6] = s;
  __syncthreads();
  if (tid == 0) out[0] = (wsum[0] + wsum[1] + wsum[2] + wsum[3]) * (1.0f / 65536.0f);
}

// ---------------------------------------------------------------------------
extern "C" void kernel_launch(void* const* d_in, const int* in_sizes, int n_in,
                              void* d_out, int out_size, void* d_ws, size_t ws_size,
                              hipStream_t stream) {
  const float* x = (const float*)d_in[0];
  const float* y = (const float*)d_in[1];
  float* out = (float*)d_out;

  char* p = (char*)d_ws;
  u16* xs = (u16*)p;            p += (size_t)512 * 16384;   // 8 MiB
  u16* ys = (u16*)p;            p += (size_t)512 * 16384;   // 8 MiB
  float* x2h = (float*)p;       p += (size_t)65536 * 4;
  float* y2h = (float*)p;       p += (size_t)65536 * 4;
  float* partials = (float*)p;  p += 4096;
  char* tail = p;
  // partial path: rowpart (1536*128 f) + colpart (512*8192 f)
  float* rowpart = (float*)tail;
  float* colpart = (float*)(tail + (size_t)1536 * 128 * 4);
  // atomic fallback: two 256KiB ordered-uint max buffers
  unsigned* rowmax_u = (unsigned*)tail;
  unsigned* colmax_u = (unsigned*)(tail + (size_t)65536 * 4);
  const size_t need_part = (size_t)(tail - (char*)d_ws) +
                           (size_t)1536 * 128 * 4 + (size_t)512 * 8192 * 4;
  const int use_part = (ws_size >= need_part) ? 1 : 0;

  if (!use_part)
    zero_kernel<<<dim3(512), dim3(256), 0, stream>>>(rowmax_u, 131072);

  pre_kernel<<<dim3(2048), dim3(256), 0, stream>>>(x, y, xs, ys, x2h, y2h);
  main_kernel<<<dim3(1536), dim3(256), 0, stream>>>(xs, ys, x2h, y2h,
                                                    rowpart, colpart,
                                                    rowmax_u, colmax_u, use_part);
  reduce_kernel<<<dim3(256), dim3(256), 0, stream>>>(rowpart, colpart,
                                                     rowmax_u, colmax_u, y2h,
                                                     partials, use_part);
  final_kernel<<<dim3(1), dim3(256), 0, stream>>>(partials, out);
}

// Round 3
// 168.805 us; speedup vs baseline: 1.1475x; 1.0566x over previous
//
#include <hip/hip_runtime.h>
#include <cstdint>
#include <cstddef>

typedef unsigned short u16;
typedef __attribute__((ext_vector_type(8))) short short8;
typedef __attribute__((ext_vector_type(8))) u16 ushort8;
typedef __attribute__((ext_vector_type(4))) float float4_t;

#define BB 8
#define NN 8192
#define DD 64
#define NTILES 64            // 8192 / 128 column tiles
#define TILE_SHORTS 8192     // 128 points * 64 k (bf16)

__device__ inline u16 f32_to_bf16(float f) {
  unsigned u = __float_as_uint(f);
  u += 0x7FFFu + ((u >> 16) & 1u);   // RNE
  return (u16)(u >> 16);
}

__device__ inline unsigned enc_ord(float f) {
  unsigned u = __float_as_uint(f);
  return (u & 0x80000000u) ? ~u : (u | 0x80000000u);
}
__device__ inline float dec_ord(unsigned u) {
  return __uint_as_float((u & 0x80000000u) ? (u & 0x7fffffffu) : ~u);
}

// ---------------------------------------------------------------------------
// K1: fp32 -> bf16 pre-swizzle into MFMA fragment chunk order + 0.5*|v|^2.
// Also zeroes the atomic col-max buffer in the fallback path (folded launch).
// Chunk layout per 128x64 tile: [I(8)][s(2)] chunks of 1KB; within a chunk
// lane l (l=q*16+rl) holds point I*16+rl, k = s*32+q*8+j (j=0..7, 16B).
// ---------------------------------------------------------------------------
__global__ __launch_bounds__(256) void pre_kernel(
    const float* __restrict__ x, const float* __restrict__ y,
    u16* __restrict__ xs, u16* __restrict__ ys,
    float* __restrict__ x2h, float* __restrict__ y2h,
    unsigned* __restrict__ colmax_u, const int use_part)
{
  const int bid = blockIdx.x;          // 2048: 0..1023 -> x, 1024..2047 -> y
  const int tid = threadIdx.x;

  if (!use_part && bid < 256) colmax_u[(bid << 8) | tid] = 0u;

  const bool isY = bid >= 1024;
  const float* src = isY ? y : x;
  u16* dst = isY ? ys : xs;
  float* s2 = isY ? y2h : x2h;

  const int row = ((bid & 1023) << 6) | (tid >> 2);   // 0..65535 = b*8192+n
  const int kq  = tid & 3;                            // 16-float chunk of D

  const float4* rp = (const float4*)(src + (size_t)row * DD + kq * 16);
  float buf[16];
  float ss = 0.f;
#pragma unroll
  for (int k = 0; k < 4; ++k) {
    float4 f = rp[k];
    buf[4*k+0] = f.x; buf[4*k+1] = f.y; buf[4*k+2] = f.z; buf[4*k+3] = f.w;
    ss += f.x*f.x + f.y*f.y + f.z*f.z + f.w*f.w;
  }
  ss += __shfl_xor(ss, 1);
  ss += __shfl_xor(ss, 2);
  if (kq == 0) s2[row] = 0.5f * ss;

  const int b  = row >> 13;
  const int n  = row & (NN - 1);
  const int nt = n >> 7;
  const int I  = (n >> 4) & 7;
  const int rl = n & 15;
  const int s  = kq >> 1;              // which K-half (MFMA index)
  const int qq0 = (kq & 1) * 2;
  u16* tb = dst + (size_t)((b << 6) | nt) * TILE_SHORTS;
#pragma unroll
  for (int t = 0; t < 2; ++t) {
    ushort8 o;
#pragma unroll
    for (int j = 0; j < 8; ++j) o[j] = f32_to_bf16(buf[t*8 + j]);
    *(ushort8*)(tb + (I*2 + s)*512 + ((qq0 + t)*16 + rl)*8) = o;
  }
}

// ---------------------------------------------------------------------------
// K2: main. Barrier-free K-loop. Block = 4 waves; each wave owns 128 rows x
// 32 cols (cols w*32..w*32+31 of each col-tile) -> col-max is wave-private,
// B fragments are wave-disjoint and loaded straight from L2-resident ys with
// a 1-iteration register prefetch. acc = xy - x2/2 via fp32 C-init.
// Grid 512 = 8 b (XCD-affine) x 64 nt; exactly 2 blocks/CU.
// ---------------------------------------------------------------------------
__global__ __launch_bounds__(256, 2) void main_kernel(
    const u16* __restrict__ xs, const u16* __restrict__ ys,
    const float* __restrict__ x2h, const float* __restrict__ y2h,
    float* __restrict__ a_min, float* __restrict__ colpart,
    unsigned* __restrict__ colmax_u, const int use_part)
{
  __shared__ float rowbuf[4][128];

  const int bid = blockIdx.x;            // 512
  const int b   = bid & 7;               // XCD-affine
  const int nt  = bid >> 3;
  const int tid = threadIdx.x;
  const int w = tid >> 6, lane = tid & 63;   // w = column-slice owner
  const int l15 = lane & 15, q = lane >> 4;
  const int n0 = nt << 7;

  // ---- A fragments: all 128 rows, both K-halves, pinned in registers ----
  const u16* xs_tile = xs + (size_t)((b << 6) | nt) * TILE_SHORTS;
  short8 afr[8][2];
#pragma unroll
  for (int i = 0; i < 8; ++i)
#pragma unroll
    for (int s = 0; s < 2; ++s)
      afr[i][s] = *(const short8*)(xs_tile + (i*2 + s)*512 + lane*8);

  // ---- C-init quads: -x2/2 per row (fp32 exact) ----
  float4_t negx2[8];
  const float* x2b = x2h + b*NN + n0;
#pragma unroll
  for (int i = 0; i < 8; ++i) {
    float4_t v = *(const float4_t*)(x2b + i*16 + q*4);
    negx2[i] = {-v[0], -v[1], -v[2], -v[3]};
  }

  float rowmax[8][4];
#pragma unroll
  for (int i = 0; i < 8; ++i)
#pragma unroll
    for (int r = 0; r < 4; ++r) rowmax[i][r] = -3.0e38f;

  const float* y2b = y2h + b*NN;
  const u16* ys_b  = ys + (size_t)(b << 6) * TILE_SHORTS;
  float* colp      = colpart + (size_t)((b << 6) | nt) * NN;
  unsigned* colu   = colmax_u + b*NN;

  // ---- register prefetch for mt = 0 ----
  short8 bcur[2][2];
  float y2cur[2];
#pragma unroll
  for (int j = 0; j < 2; ++j) {
#pragma unroll
    for (int s = 0; s < 2; ++s)
      bcur[j][s] = *(const short8*)(ys_b + ((2*w + j)*2 + s)*512 + lane*8);
    y2cur[j] = y2b[w*32 + j*16 + l15];
  }

  for (int mt = 0; mt < NTILES; ++mt) {
    // prefetch mt+1 (clamped; uniform predicate-free codegen)
    const int mtn = (mt + 1 < NTILES) ? (mt + 1) : 0;
    short8 bnext[2][2];
    float y2next[2];
    const u16* g = ys_b + (size_t)mtn * TILE_SHORTS;
#pragma unroll
    for (int j = 0; j < 2; ++j) {
#pragma unroll
      for (int s = 0; s < 2; ++s)
        bnext[j][s] = *(const short8*)(g + ((2*w + j)*2 + s)*512 + lane*8);
      y2next[j] = y2b[mtn*128 + w*32 + j*16 + l15];
    }

    float cmax[2];
#pragma unroll
    for (int j = 0; j < 2; ++j) {
      // acc = xy - x2/2 (C carries exact fp32 -x2/2); j-sequential to halve
      // live accumulators (8 x float4)
      float4_t acc[8];
#pragma unroll
      for (int i = 0; i < 8; ++i)
        acc[i] = __builtin_amdgcn_mfma_f32_16x16x32_bf16(afr[i][0], bcur[j][0], negx2[i], 0, 0, 0);
#pragma unroll
      for (int i = 0; i < 8; ++i)
        acc[i] = __builtin_amdgcn_mfma_f32_16x16x32_bf16(afr[i][1], bcur[j][1], acc[i], 0, 0, 0);

      // col side: pure max over rows in-lane
      float m01 = fmaxf(fmaxf(acc[0][0], acc[0][1]), fmaxf(acc[0][2], acc[0][3]));
#pragma unroll
      for (int i = 1; i < 8; ++i) {
        float mi = fmaxf(fmaxf(acc[i][0], acc[i][1]), fmaxf(acc[i][2], acc[i][3]));
        m01 = fmaxf(m01, mi);
      }
      cmax[j] = m01;

      // row side: rowmax = max(acc - y2/2) = -min(d^2)/2
      const float y2j = y2cur[j];
#pragma unroll
      for (int i = 0; i < 8; ++i)
#pragma unroll
        for (int r = 0; r < 4; ++r)
          rowmax[i][r] = fmaxf(rowmax[i][r], acc[i][r] - y2j);
    }

    // col-max: combine q-groups (rows) via shuffles; wave-private, no barrier
#pragma unroll
    for (int j = 0; j < 2; ++j) {
      cmax[j] = fmaxf(cmax[j], __shfl_xor(cmax[j], 16));
      cmax[j] = fmaxf(cmax[j], __shfl_xor(cmax[j], 32));
    }
    float cv = (q & 1) ? cmax[1] : cmax[0];
    const int m = (mt << 7) + w*32 + q*16 + l15;   // valid for q<2
    if (q < 2) {
      if (use_part) colp[m] = cv;
      else          atomicMax(&colu[m], enc_ord(cv));
    }

#pragma unroll
    for (int j = 0; j < 2; ++j) {
#pragma unroll
      for (int s = 0; s < 2; ++s) bcur[j][s] = bnext[j][s];
      y2cur[j] = y2next[j];
    }
  }

  // ---- row side finalize: shfl over cols (l15), then 4-wave LDS combine ----
#pragma unroll
  for (int i = 0; i < 8; ++i)
#pragma unroll
    for (int r = 0; r < 4; ++r) {
      float v = rowmax[i][r];
      v = fmaxf(v, __shfl_xor(v, 1));
      v = fmaxf(v, __shfl_xor(v, 2));
      v = fmaxf(v, __shfl_xor(v, 4));
      v = fmaxf(v, __shfl_xor(v, 8));
      rowmax[i][r] = v;
    }
  if (l15 == 0) {
#pragma unroll
    for (int i = 0; i < 8; ++i)
#pragma unroll
      for (int r = 0; r < 4; ++r)
        rowbuf[w][i*16 + q*4 + r] = rowmax[i][r];
  }
  __syncthreads();
  if (tid < 128) {
    float v = fmaxf(fmaxf(rowbuf[0][tid], rowbuf[1][tid]),
                    fmaxf(rowbuf[2][tid], rowbuf[3][tid]));   // -min(d^2)/2
    a_min[b*NN + n0 + tid] = sqrtf(fmaxf(-2.f * v, 0.f));
  }
}

// ---------------------------------------------------------------------------
// K3: col-side combine over 64 nt partials + sqrt, add a_min; block sums.
// ---------------------------------------------------------------------------
__global__ __launch_bounds__(256) void reduce_kernel(
    const float* __restrict__ colpart, const unsigned* __restrict__ colmax_u,
    const float* __restrict__ y2h, const float* __restrict__ a_min,
    float* __restrict__ partials, const int use_part)
{
  const int bid = blockIdx.x;          // 256
  const int tid = threadIdx.x;
  const int g = bid*256 + tid;         // 0..65535
  const int b = g >> 13, m = g & (NN - 1);

  float vc;
  if (use_part) {
    vc = -3.0e38f;
#pragma unroll 8
    for (int nt = 0; nt < 64; ++nt)
      vc = fmaxf(vc, colpart[(size_t)((b << 6) | nt) * NN + m]);
  } else {
    vc = dec_ord(colmax_u[g]);
  }
  float s = sqrtf(fmaxf(2.f*(y2h[g] - vc), 0.f))   // nearest-x for this y
          + a_min[g];                              // nearest-y for this x

#pragma unroll
  for (int d = 1; d < 64; d <<= 1) s += __shfl_xor(s, d);
  __shared__ float wsum[4];
  if ((tid & 63) == 0) wsum[tid >> 6] = s;
  __syncthreads();
  if (tid == 0) partials[bid] = wsum[0] + wsum[1] + wsum[2] + wsum[3];
}

// ---------------------------------------------------------------------------
// K4: final scalar
// ---------------------------------------------------------------------------
__global__ void final_kernel(const float* __restrict__ partials, float* __restrict__ out) {
  const int tid = threadIdx.x;         // 256
  float s = partials[tid];
#pragma unroll
  for (int d = 1; d < 64; d <<= 1) s += __shfl_xor(s, d);
  __shared__ float wsum[4];
  if ((tid & 63) == 0) wsum[tid >> 6] = s;
  __syncthreads();
  if (tid == 0) out[0] = (wsum[0] + wsum[1] + wsum[2] + wsum[3]) * (1.0f / 65536.0f);
}

// ---------------------------------------------------------------------------
extern "C" void kernel_launch(void* const* d_in, const int* in_sizes, int n_in,
                              void* d_out, int out_size, void* d_ws, size_t ws_size,
                              hipStream_t stream) {
  const float* x = (const float*)d_in[0];
  const float* y = (const float*)d_in[1];
  float* out = (float*)d_out;

  char* p = (char*)d_ws;
  u16* xs = (u16*)p;            p += (size_t)512 * 16384;   // 8 MiB
  u16* ys = (u16*)p;            p += (size_t)512 * 16384;   // 8 MiB
  float* x2h = (float*)p;       p += (size_t)65536 * 4;
  float* y2h = (float*)p;       p += (size_t)65536 * 4;
  float* a_min = (float*)p;     p += (size_t)65536 * 4;
  float* partials = (float*)p;  p += 4096;
  char* tail = p;
  // partial path: colpart (512 * 8192 f = 16 MiB); fallback: 256 KiB atomics
  float* colpart = (float*)tail;
  unsigned* colmax_u = (unsigned*)tail;
  const size_t need_part = (size_t)(tail - (char*)d_ws) + (size_t)512 * 8192 * 4;
  const int use_part = (ws_size >= need_part) ? 1 : 0;

  pre_kernel<<<dim3(2048), dim3(256), 0, stream>>>(x, y, xs, ys, x2h, y2h,
                                                   colmax_u, use_part);
  main_kernel<<<dim3(512), dim3(256), 0, stream>>>(xs, ys, x2h, y2h, a_min,
                                                   colpart, colmax_u, use_part);
  reduce_kernel<<<dim3(256), dim3(256), 0, stream>>>(colpart, colmax_u, y2h,
                                                     a_min, partials, use_part);
  final_kernel<<<dim3(1), dim3(256), 0, stream>>>(partials, out);
}